// Round 12
// baseline (49.214 us; speedup 1.0000x reference)
//
#include <hip/hip_runtime.h>

typedef float f4 __attribute__((ext_vector_type(4)));

#define Hdim 64
#define Wdim 64
#define Cdim 256
#define HW (Hdim * Wdim)

// LDS-staged rewrite of the r5/r11 champion. Wall identified in r11: per-CU
// vector-return BW (~64B/clk): 3.6MB/CU of window-overlap global reads.
// Fix: stage 32c x 7row x 64w chunks in LDS once per phase (global 1.8MB/CU,
// each element read once), serve the 3x-overlap window reads from the LDS
// pipe (128B/clk, separate). Geometry unchanged: 512 blocks (b,h,w-half),
// 512 thr, XCD decode bid&7 -> (batch, 32-row band), 2.4MB < 4MB L2.
// smBuf holds sim then attn in-place (read-before-overwrite across barriers)
// to keep static LDS = 65,408B <= 64KB. Natural register allocation (no
// min-waves clamp: r6-r9 ledger). OOB rows: staged clamped, never read;
// sim stays 0 and still enters softmax (reference zero-pad semantics).
__global__ __launch_bounds__(512) void selfattn_kernel(const float* __restrict__ x,
                                                       float* __restrict__ out)
{
    const int bid = blockIdx.x;
    const int k   = bid & 7;
    const int seq = bid >> 3;            // 0..63
    const int b   = k >> 1;
    const int h   = (k & 1) * 32 + (seq >> 1);
    const int wbase = (seq & 1) * 32;    // w-half
    const int t = threadIdx.x;           // 0..511

    __shared__ __align__(16) float xbuf[32 * 7 * 64];   // 57,344B chunk buffer
    __shared__ __align__(16) float smBuf[49][32];       // 6,272B sim -> attn (in-place)
    __shared__ float redBuf[7][32];                     // 896B
    __shared__ float psumBuf[7][32];                    // 896B

    const float* xb = x + (size_t)b * (Cdim * HW);

    // clamped source rows (same every chunk; OOB rows staged but never read)
    int grows[7];
    #pragma unroll
    for (int r = 0; r < 7; ++r) {
        int g = h + r - 3;
        grows[r] = g < 0 ? 0 : (g > 63 ? 63 : g);
    }
    // staging decode: thread -> (channel-in-chunk, w-quad), 7 rows each
    const int scc = t >> 4;              // 0..31
    const int swq = t & 15;              // 0..15

    // ---- phase A lane decode ----
    const int w4A = t & 7;               // 8 w-groups of 4 (32 wide)
    const int cpA = (t >> 3) & 7;        // 8 channel partitions (lane bits 3..5)
    const int dyA = t >> 6;              // wave id; 7 = stage-only wave
    const int lw0A = w4A * 4;
    const int w0gA = wbase + lw0A;
    const int rowA = h + dyA - 3;
    const bool rowAok = (dyA < 7) && (rowA >= 0) && (rowA < Hdim);
    const bool hasLA = (w0gA != 0);
    const bool hasRA = (w0gA != 60);

    float sim[7][4];
    #pragma unroll
    for (int dx = 0; dx < 7; ++dx)
        #pragma unroll
        for (int p = 0; p < 4; ++p) sim[dx][p] = 0.f;

    // ================= PHASE A: sim over 8 chunks of 32 channels =================
    for (int ch = 0; ch < 8; ++ch) {
        // stage chunk: each thread 7 f4 (rows) for its (scc, swq)
        {
            const float* sb = xb + (size_t)(ch * 32 + scc) * HW + swq * 4;
            float* db = &xbuf[(scc * 7) * 64 + swq * 4];
            #pragma unroll
            for (int r = 0; r < 7; ++r) {
                f4 v = *(const f4*)(sb + grows[r] * 64);
                *(f4*)(db + r * 64) = v;
            }
        }
        __syncthreads();
        if (rowAok) {
            #pragma unroll
            for (int j = 0; j < 4; ++j) {
                const int cc = cpA + j * 8;
                const float* rp = &xbuf[(cc * 7 + dyA) * 64];
                const float* cq = &xbuf[(cc * 7 + 3) * 64];
                float f[12];
                if (hasLA) { f4 v = *(const f4*)(rp + w0gA - 4);
                    f[0]=v.x; f[1]=v.y; f[2]=v.z; f[3]=v.w; }
                else { f[0]=0.f; f[1]=0.f; f[2]=0.f; f[3]=0.f; }
                { f4 v = *(const f4*)(rp + w0gA);
                    f[4]=v.x; f[5]=v.y; f[6]=v.z; f[7]=v.w; }
                if (hasRA) { f4 v = *(const f4*)(rp + w0gA + 4);
                    f[8]=v.x; f[9]=v.y; f[10]=v.z; f[11]=v.w; }
                else { f[8]=0.f; f[9]=0.f; f[10]=0.f; f[11]=0.f; }
                f4 cen = *(const f4*)(cq + w0gA);
                #pragma unroll
                for (int dx = 0; dx < 7; ++dx)
                    #pragma unroll
                    for (int p = 0; p < 4; ++p)
                        sim[dx][p] += cen[p] * f[dx + p + 1];
            }
        }
        __syncthreads();
    }

    // reduce over 8 channel partitions (lane bits 3..5), write sims
    #pragma unroll
    for (int dx = 0; dx < 7; ++dx)
        #pragma unroll
        for (int p = 0; p < 4; ++p) {
            float v = sim[dx][p];
            v += __shfl_xor(v, 8);
            v += __shfl_xor(v, 16);
            v += __shfl_xor(v, 32);
            sim[dx][p] = v;
        }
    if (dyA < 7 && cpA == 0) {
        #pragma unroll
        for (int dx = 0; dx < 7; ++dx)
            *(f4*)&smBuf[dyA * 7 + dx][lw0A] = *(const f4*)sim[dx];
    }
    __syncthreads();

    // ================= Softmax over k=49 (attn written in-place into smBuf) =====
    {
        const int w  = t & 31;
        const int kc = t >> 5;    // 0..15; kc<7 active
        float sred[7], e[7];
        if (kc < 7) {
            float lmax = -3.0e38f;
            #pragma unroll
            for (int jj = 0; jj < 7; ++jj) {
                float s = smBuf[kc * 7 + jj][w];
                sred[jj] = s;
                lmax = fmaxf(lmax, s);
            }
            redBuf[kc][w] = lmax;
        }
        __syncthreads();
        if (kc < 7) {
            float m = redBuf[0][w];
            #pragma unroll
            for (int q = 1; q < 7; ++q) m = fmaxf(m, redBuf[q][w]);
            float ps = 0.f;
            #pragma unroll
            for (int jj = 0; jj < 7; ++jj) {
                e[jj] = __expf(sred[jj] - m);
                ps += e[jj];
            }
            psumBuf[kc][w] = ps;
        }
        __syncthreads();
        if (kc < 7) {
            float l = psumBuf[0][w];
            #pragma unroll
            for (int q = 1; q < 7; ++q) l += psumBuf[q][w];
            float rinv = 1.0f / l;
            #pragma unroll
            for (int jj = 0; jj < 7; ++jj)
                smBuf[kc * 7 + jj][w] = e[jj] * rinv;   // attn, in-place
        }
    }
    __syncthreads();

    // ================= PHASE B: out over 8 chunks ==============================
    // thread = (w4: bits 0..2, dup: bits 3..4 -> dy pair, ccI: bits 5..8)
    const int w4B = t & 7;
    const int dup = (t >> 3) & 3;
    const int ccI = t >> 5;              // 0..15
    const int lw0B = w4B * 4;
    const int w0gB = wbase + lw0B;
    const bool hasLB = (w0gB != 0);
    const bool hasRB = (w0gB != 60);
    const int dyB0 = dup * 2;
    const int dyB1 = dup * 2 + 1;        // 7 = invalid (dup==3)
    const int rowB0 = h + dyB0 - 3;
    const int rowB1 = h + dyB1 - 3;
    const bool ok0 = (rowB0 >= 0) && (rowB0 < Hdim);
    const bool ok1 = (dyB1 < 7) && (rowB1 >= 0) && (rowB1 < Hdim);

    // attn for this thread's dy pair, held in registers across all chunks
    float a0[7][4], a1[7][4];
    #pragma unroll
    for (int dx = 0; dx < 7; ++dx) {
        f4 v = *(const f4*)&smBuf[dyB0 * 7 + dx][lw0B];
        a0[dx][0]=v.x; a0[dx][1]=v.y; a0[dx][2]=v.z; a0[dx][3]=v.w;
        if (dyB1 < 7) {
            f4 u = *(const f4*)&smBuf[dyB1 * 7 + dx][lw0B];
            a1[dx][0]=u.x; a1[dx][1]=u.y; a1[dx][2]=u.z; a1[dx][3]=u.w;
        } else {
            a1[dx][0]=0.f; a1[dx][1]=0.f; a1[dx][2]=0.f; a1[dx][3]=0.f;
        }
    }

    for (int ch = 0; ch < 8; ++ch) {
        __syncthreads();   // attn reads (first iter) / prior compute done before restage
        {
            const float* sb = xb + (size_t)(ch * 32 + scc) * HW + swq * 4;
            float* db = &xbuf[(scc * 7) * 64 + swq * 4];
            #pragma unroll
            for (int r = 0; r < 7; ++r) {
                f4 v = *(const f4*)(sb + grows[r] * 64);
                *(f4*)(db + r * 64) = v;
            }
        }
        __syncthreads();

        float accA[4] = {0.f, 0.f, 0.f, 0.f};
        float accB[4] = {0.f, 0.f, 0.f, 0.f};
        #pragma unroll
        for (int ci = 0; ci < 2; ++ci) {
            const int cc = ccI + ci * 16;
            float* acc = ci ? accB : accA;
            #pragma unroll
            for (int half = 0; half < 2; ++half) {
                const int dy = half ? dyB1 : dyB0;
                const bool ok = half ? ok1 : ok0;
                if (!ok) continue;
                const float (*aa)[4] = half ? a1 : a0;
                const float* rp = &xbuf[(cc * 7 + dy) * 64];
                float f[12];
                if (hasLB) { f4 v = *(const f4*)(rp + w0gB - 4);
                    f[0]=v.x; f[1]=v.y; f[2]=v.z; f[3]=v.w; }
                else { f[0]=0.f; f[1]=0.f; f[2]=0.f; f[3]=0.f; }
                { f4 v = *(const f4*)(rp + w0gB);
                    f[4]=v.x; f[5]=v.y; f[6]=v.z; f[7]=v.w; }
                if (hasRB) { f4 v = *(const f4*)(rp + w0gB + 4);
                    f[8]=v.x; f[9]=v.y; f[10]=v.z; f[11]=v.w; }
                else { f[8]=0.f; f[9]=0.f; f[10]=0.f; f[11]=0.f; }
                #pragma unroll
                for (int dx = 0; dx < 7; ++dx)
                    #pragma unroll
                    for (int p = 0; p < 4; ++p)
                        acc[p] += aa[dx][p] * f[dx + p + 1];
            }
        }
        // reduce over dup (lane bits 3..4); all lanes participate in shfl
        #pragma unroll
        for (int p = 0; p < 4; ++p) {
            accA[p] += __shfl_xor(accA[p], 8);
            accA[p] += __shfl_xor(accA[p], 16);
            accB[p] += __shfl_xor(accB[p], 8);
            accB[p] += __shfl_xor(accB[p], 16);
        }
        if (dup == 0) {
            float* ob = out + (size_t)b * (Cdim * HW) + h * Wdim + w0gB;
            *(f4*)(ob + (size_t)(ch * 32 + ccI) * HW)      = *(const f4*)accA;
            *(f4*)(ob + (size_t)(ch * 32 + ccI + 16) * HW) = *(const f4*)accB;
        }
    }
}

extern "C" void kernel_launch(void* const* d_in, const int* in_sizes, int n_in,
                              void* d_out, int out_size, void* d_ws, size_t ws_size,
                              hipStream_t stream)
{
    const float* x = (const float*)d_in[0];
    float* out = (float*)d_out;
    selfattn_kernel<<<dim3(512), 512, 0, stream>>>(x, out);
}

// Round 13
// 33.208 us; speedup vs baseline: 1.4820x; 1.4820x over previous
//
#include <hip/hip_runtime.h>

typedef float f4 __attribute__((ext_vector_type(4)));
typedef _Float16 h2 __attribute__((ext_vector_type(2)));

#define Hdim 64
#define Wdim 64
#define Cdim 256
#define HW (Hdim * Wdim)

// v_dot2_f32_f16: d = a.x*b.x + a.y*b.y + c  (fp32 accumulate)
__device__ __forceinline__ float fdot2f(h2 a, h2 b, float c) {
#if __has_builtin(__builtin_amdgcn_fdot2)
    return __builtin_amdgcn_fdot2(a, b, c, false);
#else
    float d;
    asm("v_dot2_f32_f16 %0, %1, %2, %3" : "=v"(d) : "v"(a), "v"(b), "v"(c));
    return d;
#endif
}

// ---------------------------------------------------------------------------
// Pack kernel: x fp32 [b][c][h][w] -> ws half2 [b][c/2][h][w] = {x[2cp],x[2cp+1]}
// 524288 threads, fully coalesced both sides.
// ---------------------------------------------------------------------------
__global__ __launch_bounds__(512) void pack_kernel(const float* __restrict__ x,
                                                   float* __restrict__ pw)
{
    const int tid = blockIdx.x * 512 + threadIdx.x;   // 0..524287
    const int wq = tid & 15;
    const int h  = (tid >> 4) & 63;
    const int cp = (tid >> 10) & 127;
    const int b  = tid >> 17;
    const float* s0 = x + ((size_t)b * Cdim + 2 * cp) * HW + h * 64 + wq * 4;
    f4 v0 = *(const f4*)s0;
    f4 v1 = *(const f4*)(s0 + HW);
    f4 ov;
    #pragma unroll
    for (int p = 0; p < 4; ++p) {
        h2 o;
        o[0] = (_Float16)v0[p];
        o[1] = (_Float16)v1[p];
        ov[p] = __builtin_bit_cast(float, o);
    }
    *(f4*)(pw + ((size_t)b * 128 + cp) * HW + h * 64 + wq * 4) = ov;
}

// ---------------------------------------------------------------------------
// Main kernel: r11 champion structure (512 blocks (b,h,w-half) x 512 thr,
// XCD decode bid&7 -> (batch, 32-row band)), on packed-f16 data.
// Phase A: window f4 load = 4w x 2ch; 28 v_dot2_f32_f16 per iter (fp32 acc).
// Phase B: attn packed (a,a) in LDS; v_pk_fma_f16, f16 acc (out ~= 1.0*x).
// ---------------------------------------------------------------------------
__global__ __launch_bounds__(512, 2) void selfattn_f16(const float* __restrict__ pwf,
                                                       float* __restrict__ out)
{
    const int bid = blockIdx.x;
    const int k   = bid & 7;
    const int seq = bid >> 3;            // 0..63
    const int b   = k >> 1;
    const int h   = (k & 1) * 32 + (seq >> 1);
    const int wbase = (seq & 1) * 32;    // w-half
    const int t = threadIdx.x;           // 0..511

    __shared__ float simRed[49][32];
    __shared__ __align__(16) h2 attnH[49][32];   // (a,a) packed
    __shared__ float redBuf[7][32];
    __shared__ float psumBuf[7][32];

    const float* pw = pwf + (size_t)b * (128 * HW);   // h2 elements viewed as float

    // ---------------- Phase A: sim[k][w] over 128 channel-pairs ----------------
    // thread = (w4: bits 0..2, cp: bits 3..5, dy: wave). iter i: pair = i*8+cp.
    {
        const int w4 = t & 7;
        const int cp = (t >> 3) & 7;
        const int dy = t >> 6;           // wave-uniform; dy==7 idle
        const int lw0 = w4 * 4;
        const int w0g = wbase + lw0;

        if (dy < 7) {
            float sim[7][4];
            #pragma unroll
            for (int dx = 0; dx < 7; ++dx)
                #pragma unroll
                for (int p = 0; p < 4; ++p) sim[dx][p] = 0.f;

            const int row = h + dy - 3;
            if (row >= 0 && row < Hdim) {
                const bool hasL = (w0g != 0);
                const bool hasR = (w0g != 60);
                const float* xr = pw + (size_t)cp * HW + row * 64;
                const float* xc = pw + (size_t)cp * HW + h   * 64;
                for (int i = 0; i < 16; ++i) {
                    float fw[12];
                    if (hasL) {
                        f4 v = *(const f4*)(xr + w0g - 4);
                        fw[0]=v.x; fw[1]=v.y; fw[2]=v.z; fw[3]=v.w;
                    } else { fw[0]=0.f; fw[1]=0.f; fw[2]=0.f; fw[3]=0.f; }
                    {
                        f4 v = *(const f4*)(xr + w0g);
                        fw[4]=v.x; fw[5]=v.y; fw[6]=v.z; fw[7]=v.w;
                    }
                    if (hasR) {
                        f4 v = *(const f4*)(xr + w0g + 4);
                        fw[8]=v.x; fw[9]=v.y; fw[10]=v.z; fw[11]=v.w;
                    } else { fw[8]=0.f; fw[9]=0.f; fw[10]=0.f; fw[11]=0.f; }
                    f4 cen = *(const f4*)(xc + w0g);
                    h2 f2[12], cen2[4];
                    #pragma unroll
                    for (int j = 0; j < 12; ++j) f2[j] = __builtin_bit_cast(h2, fw[j]);
                    #pragma unroll
                    for (int p = 0; p < 4; ++p) cen2[p] = __builtin_bit_cast(h2, cen[p]);
                    #pragma unroll
                    for (int dx = 0; dx < 7; ++dx)
                        #pragma unroll
                        for (int p = 0; p < 4; ++p)
                            sim[dx][p] = fdot2f(cen2[p], f2[dx + p + 1], sim[dx][p]);
                    xr += 8 * HW;
                    xc += 8 * HW;
                }
            }
            // reduce over 8 channel partitions (lane bits 3..5)
            #pragma unroll
            for (int dx = 0; dx < 7; ++dx)
                #pragma unroll
                for (int p = 0; p < 4; ++p) {
                    float v = sim[dx][p];
                    v += __shfl_xor(v, 8);
                    v += __shfl_xor(v, 16);
                    v += __shfl_xor(v, 32);
                    sim[dx][p] = v;
                }
            if (cp == 0) {
                #pragma unroll
                for (int dx = 0; dx < 7; ++dx)
                    *(f4*)&simRed[dy * 7 + dx][lw0] = *(const f4*)sim[dx];
            }
        }
    }
    __syncthreads();

    // ---------------- Softmax over k=49; attn stored as (a,a) half2 ----------------
    {
        const int w  = t & 31;
        const int kc = t >> 5;    // 0..15; kc<7 active
        float sred[7], e[7];
        if (kc < 7) {
            float lmax = -3.0e38f;
            #pragma unroll
            for (int jj = 0; jj < 7; ++jj) {
                float s = simRed[kc * 7 + jj][w];
                sred[jj] = s;
                lmax = fmaxf(lmax, s);
            }
            redBuf[kc][w] = lmax;
        }
        __syncthreads();
        if (kc < 7) {
            float m = redBuf[0][w];
            #pragma unroll
            for (int q = 1; q < 7; ++q) m = fmaxf(m, redBuf[q][w]);
            float ps = 0.f;
            #pragma unroll
            for (int jj = 0; jj < 7; ++jj) {
                e[jj] = __expf(sred[jj] - m);
                ps += e[jj];
            }
            psumBuf[kc][w] = ps;
        }
        __syncthreads();
        if (kc < 7) {
            float l = psumBuf[0][w];
            #pragma unroll
            for (int q = 1; q < 7; ++q) l += psumBuf[q][w];
            float rinv = 1.0f / l;
            #pragma unroll
            for (int jj = 0; jj < 7; ++jj) {
                _Float16 ah = (_Float16)(e[jj] * rinv);
                h2 av; av[0] = ah; av[1] = ah;
                attnH[kc * 7 + jj][w] = av;
            }
        }
    }
    __syncthreads();

    // ---------------- Phase B: out via v_pk_fma_f16 ----------------
    // thread = (w4: bits 0..2, ci: bits 3..8) -> pairs 2ci,2ci+1 = channels 4ci..4ci+3
    {
        const int w4 = t & 7;
        const int ci = t >> 3;           // 0..63
        const int lw0 = w4 * 4;
        const int w0g = wbase + lw0;
        const bool hasL = (w0g != 0);
        const bool hasR = (w0g != 60);

        h2 acc2[2][4];
        #pragma unroll
        for (int pr = 0; pr < 2; ++pr)
            #pragma unroll
            for (int p = 0; p < 4; ++p) { acc2[pr][p][0] = (_Float16)0; acc2[pr][p][1] = (_Float16)0; }

        for (int dy = 0; dy < 7; ++dy) {
            const int row = h + dy - 3;
            if (row < 0 || row >= Hdim) continue;   // block-uniform
            h2 a2[7][4];
            #pragma unroll
            for (int dx = 0; dx < 7; ++dx) {
                f4 v = *(const f4*)&attnH[dy * 7 + dx][lw0];
                #pragma unroll
                for (int p = 0; p < 4; ++p) a2[dx][p] = __builtin_bit_cast(h2, v[p]);
            }
            #pragma unroll
            for (int pr = 0; pr < 2; ++pr) {
                const float* xr = pw + (size_t)(2 * ci + pr) * HW + row * 64;
                float fw[12];
                if (hasL) {
                    f4 v = *(const f4*)(xr + w0g - 4);
                    fw[0]=v.x; fw[1]=v.y; fw[2]=v.z; fw[3]=v.w;
                } else { fw[0]=0.f; fw[1]=0.f; fw[2]=0.f; fw[3]=0.f; }
                {
                    f4 v = *(const f4*)(xr + w0g);
                    fw[4]=v.x; fw[5]=v.y; fw[6]=v.z; fw[7]=v.w;
                }
                if (hasR) {
                    f4 v = *(const f4*)(xr + w0g + 4);
                    fw[8]=v.x; fw[9]=v.y; fw[10]=v.z; fw[11]=v.w;
                } else { fw[8]=0.f; fw[9]=0.f; fw[10]=0.f; fw[11]=0.f; }
                h2 f2[12];
                #pragma unroll
                for (int j = 0; j < 12; ++j) f2[j] = __builtin_bit_cast(h2, fw[j]);
                #pragma unroll
                for (int dx = 0; dx < 7; ++dx)
                    #pragma unroll
                    for (int p = 0; p < 4; ++p)
                        acc2[pr][p] += a2[dx][p] * f2[dx + p + 1];   // v_pk_fma_f16
            }
        }

        float* ob = out + (size_t)b * (Cdim * HW) + h * Wdim + w0g;
        #pragma unroll
        for (int pr = 0; pr < 2; ++pr) {
            f4 o0, o1;
            #pragma unroll
            for (int p = 0; p < 4; ++p) {
                o0[p] = (float)acc2[pr][p][0];
                o1[p] = (float)acc2[pr][p][1];
            }
            const int c0 = 4 * ci + 2 * pr;
            *(f4*)(ob + (size_t)c0 * HW)       = o0;
            *(f4*)(ob + (size_t)(c0 + 1) * HW) = o1;
        }
    }
}

// ---------------------------------------------------------------------------
// Fallback: r11 champion (40.0us) if ws is too small for the packed copy.
// ---------------------------------------------------------------------------
__global__ __launch_bounds__(512, 2) void selfattn_fb(const float* __restrict__ x,
                                                      float* __restrict__ out)
{
    const int bid = blockIdx.x;
    const int k   = bid & 7;
    const int seq = bid >> 3;
    const int b   = k >> 1;
    const int h   = (k & 1) * 32 + (seq >> 1);
    const int wbase = (seq & 1) * 32;
    const int t = threadIdx.x;

    __shared__ float simRed[49][32];
    __shared__ float attnBuf[49][32];
    __shared__ float redBuf[7][32];
    __shared__ float psumBuf[7][32];

    const float* xb = x + (size_t)b * (Cdim * HW);

    {
        const int w4 = t & 7;
        const int cp = (t >> 3) & 7;
        const int dy = t >> 6;
        const int lw0 = w4 * 4;
        const int w0g = wbase + lw0;

        if (dy < 7) {
            float sim[7][4];
            #pragma unroll
            for (int dx = 0; dx < 7; ++dx)
                #pragma unroll
                for (int p = 0; p < 4; ++p) sim[dx][p] = 0.f;

            const int row = h + dy - 3;
            if (row >= 0 && row < Hdim) {
                const bool hasL = (w0g != 0);
                const bool hasR = (w0g != 60);
                const float* xrA = xb + (size_t)cp * HW + row * Wdim;
                const float* xcA = xb + (size_t)cp * HW + h   * Wdim;
                const float* xrB = xrA + (size_t)128 * HW;
                const float* xcB = xcA + (size_t)128 * HW;
                #pragma unroll 2
                for (int i = 0; i < 16; ++i) {
                    float fA[12], fB[12];
                    if (hasL) {
                        f4 v = *(const f4*)(xrA + w0g - 4);
                        fA[0]=v.x; fA[1]=v.y; fA[2]=v.z; fA[3]=v.w;
                    } else { fA[0]=0.f; fA[1]=0.f; fA[2]=0.f; fA[3]=0.f; }
                    {
                        f4 v = *(const f4*)(xrA + w0g);
                        fA[4]=v.x; fA[5]=v.y; fA[6]=v.z; fA[7]=v.w;
                    }
                    if (hasR) {
                        f4 v = *(const f4*)(xrA + w0g + 4);
                        fA[8]=v.x; fA[9]=v.y; fA[10]=v.z; fA[11]=v.w;
                    } else { fA[8]=0.f; fA[9]=0.f; fA[10]=0.f; fA[11]=0.f; }
                    if (hasL) {
                        f4 v = *(const f4*)(xrB + w0g - 4);
                        fB[0]=v.x; fB[1]=v.y; fB[2]=v.z; fB[3]=v.w;
                    } else { fB[0]=0.f; fB[1]=0.f; fB[2]=0.f; fB[3]=0.f; }
                    {
                        f4 v = *(const f4*)(xrB + w0g);
                        fB[4]=v.x; fB[5]=v.y; fB[6]=v.z; fB[7]=v.w;
                    }
                    if (hasR) {
                        f4 v = *(const f4*)(xrB + w0g + 4);
                        fB[8]=v.x; fB[9]=v.y; fB[10]=v.z; fB[11]=v.w;
                    } else { fB[8]=0.f; fB[9]=0.f; fB[10]=0.f; fB[11]=0.f; }
                    f4 cenA = *(const f4*)(xcA + w0g);
                    f4 cenB = *(const f4*)(xcB + w0g);
                    #pragma unroll
                    for (int dx = 0; dx < 7; ++dx)
                        #pragma unroll
                        for (int p = 0; p < 4; ++p)
                            sim[dx][p] += cenA[p] * fA[dx + p + 1]
                                        + cenB[p] * fB[dx + p + 1];
                    xrA += 8 * HW;  xcA += 8 * HW;
                    xrB += 8 * HW;  xcB += 8 * HW;
                }
            }
            #pragma unroll
            for (int dx = 0; dx < 7; ++dx)
                #pragma unroll
                for (int p = 0; p < 4; ++p) {
                    float v = sim[dx][p];
                    v += __shfl_xor(v, 8);
                    v += __shfl_xor(v, 16);
                    v += __shfl_xor(v, 32);
                    sim[dx][p] = v;
                }
            if (cp == 0) {
                #pragma unroll
                for (int dx = 0; dx < 7; ++dx)
                    *(f4*)&simRed[dy * 7 + dx][lw0] = *(const f4*)sim[dx];
            }
        }
    }
    __syncthreads();

    {
        const int w  = t & 31;
        const int kc = t >> 5;
        float sred[7], e[7];
        if (kc < 7) {
            float lmax = -3.0e38f;
            #pragma unroll
            for (int jj = 0; jj < 7; ++jj) {
                float s = simRed[kc * 7 + jj][w];
                sred[jj] = s;
                lmax = fmaxf(lmax, s);
            }
            redBuf[kc][w] = lmax;
        }
        __syncthreads();
        if (kc < 7) {
            float m = redBuf[0][w];
            #pragma unroll
            for (int q = 1; q < 7; ++q) m = fmaxf(m, redBuf[q][w]);
            float ps = 0.f;
            #pragma unroll
            for (int jj = 0; jj < 7; ++jj) {
                e[jj] = __expf(sred[jj] - m);
                ps += e[jj];
            }
            psumBuf[kc][w] = ps;
        }
        __syncthreads();
        if (kc < 7) {
            float l = psumBuf[0][w];
            #pragma unroll
            for (int q = 1; q < 7; ++q) l += psumBuf[q][w];
            float rinv = 1.0f / l;
            #pragma unroll
            for (int jj = 0; jj < 7; ++jj)
                attnBuf[kc * 7 + jj][w] = e[jj] * rinv;
        }
    }
    __syncthreads();

    {
        const int w4 = t & 7;
        const int ci = t >> 3;
        const int lw0 = w4 * 4;
        const int w0g = wbase + lw0;
        const int c0 = ci * 4;
        const bool hasL = (w0g != 0);
        const bool hasR = (w0g != 60);

        float acc[4][4];
        #pragma unroll
        for (int ch = 0; ch < 4; ++ch)
            #pragma unroll
            for (int p = 0; p < 4; ++p) acc[ch][p] = 0.f;

        for (int dy = 0; dy < 7; ++dy) {
            const int row = h + dy - 3;
            if (row < 0 || row >= Hdim) continue;
            float a[7][4];
            #pragma unroll
            for (int dx = 0; dx < 7; ++dx) {
                f4 v = *(const f4*)&attnBuf[dy * 7 + dx][lw0];
                a[dx][0]=v.x; a[dx][1]=v.y; a[dx][2]=v.z; a[dx][3]=v.w;
            }
            const float* xr = xb + (size_t)c0 * HW + row * Wdim;
            #pragma unroll
            for (int ch = 0; ch < 4; ++ch) {
                float fw[12];
                if (hasL) {
                    f4 v = *(const f4*)(xr + w0g - 4);
                    fw[0]=v.x; fw[1]=v.y; fw[2]=v.z; fw[3]=v.w;
                } else { fw[0]=0.f; fw[1]=0.f; fw[2]=0.f; fw[3]=0.f; }
                {
                    f4 v = *(const f4*)(xr + w0g);
                    fw[4]=v.x; fw[5]=v.y; fw[6]=v.z; fw[7]=v.w;
                }
                if (hasR) {
                    f4 v = *(const f4*)(xr + w0g + 4);
                    fw[8]=v.x; fw[9]=v.y; fw[10]=v.z; fw[11]=v.w;
                } else { fw[8]=0.f; fw[9]=0.f; fw[10]=0.f; fw[11]=0.f; }
                #pragma unroll
                for (int dx = 0; dx < 7; ++dx)
                    #pragma unroll
                    for (int p = 0; p < 4; ++p)
                        acc[ch][p] += a[dx][p] * fw[dx + p + 1];
                xr += HW;
            }
        }

        float* ob = out + (size_t)b * (Cdim * HW) + h * Wdim + wbase;
        #pragma unroll
        for (int ch = 0; ch < 4; ++ch)
            *(f4*)(ob + (size_t)(c0 + ch) * HW + lw0) = *(const f4*)acc[ch];
    }
}

extern "C" void kernel_launch(void* const* d_in, const int* in_sizes, int n_in,
                              void* d_out, int out_size, void* d_ws, size_t ws_size,
                              hipStream_t stream)
{
    const float* x = (const float*)d_in[0];
    float* out = (float*)d_out;
    const size_t need = (size_t)4 * 128 * HW * 4;   // 8 MB packed half2
    if (ws_size >= need) {
        float* pw = (float*)d_ws;
        pack_kernel<<<dim3(1024), 512, 0, stream>>>(x, pw);
        selfattn_f16<<<dim3(512), 512, 0, stream>>>(pw, out);
    } else {
        selfattn_fb<<<dim3(512), 512, 0, stream>>>(x, out);
    }
}